// Round 6
// baseline (757.705 us; speedup 1.0000x reference)
//
#include <hip/hip_runtime.h>
#include <cstdint>

// ---------------------------------------------------------------------------
// GCN: 3x GCNConv(+ELU) + linear head.
// CSR build (no per-edge global atomics, coalesced writes):
//   A) bucket_hist: global per-bucket counts (bucket = dst>>8)
//   B) bucket_scan: prefix -> boff/gcur
//   C) bucket_scatter: per-block LDS counting-sort reorder of a 4096-edge
//      tile, then run-contiguous coalesced writes into bedge
//   D) sort_deg: per-bucket LDS hist (per node x src-quarter) -> row_ptr,
//      rp4 (intra-row quarter boundaries), dinv
//   E) sort_scatter: bedge -> perm in (node, src-quarter) order, norm fused
// Aggregation: A(XW)=(AX)W so gather passes run at F=16,16,32. agg4 loops
// src-quarters (phase working set 1.6-3.2MB fits per-XCD L2); perm is read
// non-temporally so the xw slice stays L2-resident.
// ---------------------------------------------------------------------------

typedef float __attribute__((ext_vector_type(4))) f4v;

__device__ inline int2 ldnt2(const int2* p) {
    long long v = __builtin_nontemporal_load((const long long*)p);
    int2 r;
    r.x = (int)(unsigned)(v & 0xFFFFFFFFLL);
    r.y = (int)(unsigned)((unsigned long long)v >> 32);
    return r;
}
__device__ inline float4 ldnt4(const float4* p) {
    f4v v = __builtin_nontemporal_load((const f4v*)p);
    float4 r;
    r.x = v.x; r.y = v.y; r.z = v.z; r.w = v.w;
    return r;
}
__device__ inline void stnt4(float4* p, float4 r) {
    f4v v;
    v.x = r.x; v.y = r.y; v.z = r.z; v.w = r.w;
    __builtin_nontemporal_store(v, (f4v*)p);
}

// ---- Pass A: per-bucket edge counts. bucket = dst >> 8.
__global__ void __launch_bounds__(256) bucket_hist(const int* __restrict__ dst,
                                                   int* __restrict__ bcnt,
                                                   int E, int nbuck, int chunk) {
    __shared__ int h[512];
    for (int i = threadIdx.x; i < 512; i += 256) h[i] = 0;
    __syncthreads();
    int c0 = blockIdx.x * chunk;
    int c1 = min(E, c0 + chunk);
    for (int i = c0 + threadIdx.x; i < c1; i += 256)
        atomicAdd(&h[((unsigned)dst[i]) >> 8], 1);
    __syncthreads();
    for (int i = threadIdx.x; i < nbuck; i += 256)
        if (h[i]) atomicAdd(&bcnt[i], h[i]);
}

// ---- scan of bucket counts -> boff[nbuck+1], global cursors.
__global__ void __launch_bounds__(512) bucket_scan(const int* __restrict__ bcnt,
                                                   int* __restrict__ boff,
                                                   int* __restrict__ gcur,
                                                   int nbuck) {
    __shared__ int part[512];
    int t = threadIdx.x;
    part[t] = (t < nbuck) ? bcnt[t] : 0;
    __syncthreads();
    for (int off = 1; off < 512; off <<= 1) {
        int v = part[t];
        int a = (t >= off) ? part[t - off] : 0;
        __syncthreads();
        part[t] = v + a;
        __syncthreads();
    }
    if (t < nbuck) {
        int excl = (t > 0) ? part[t - 1] : 0;
        boff[t] = excl;
        gcur[t] = excl;
        if (t == nbuck - 1) boff[nbuck] = part[t];  // == E
    }
}

// ---- Pass C: LDS-reorder scatter. TILE=4096 edges/block.
__global__ void __launch_bounds__(256) bucket_scatter(const int* __restrict__ src,
                                                      const int* __restrict__ dst,
                                                      const float* __restrict__ w,
                                                      int* __restrict__ gcur,
                                                      int2* __restrict__ bedge,
                                                      int E) {
    constexpr int TILE = 4096;
    __shared__ int h[512];
    __shared__ int lcnt[512];
    __shared__ int lofs[512];
    __shared__ int gb[512];
    __shared__ int part[256];
    __shared__ int2 sedge[TILE];
    __shared__ unsigned short sbuck[TILE];

    int t = threadIdx.x;
    int c0 = blockIdx.x * TILE;
    int mtile = min(TILE, E - c0);

    for (int i = t; i < 512; i += 256) { h[i] = 0; lcnt[i] = 0; }
    __syncthreads();

    int  my_dst[16];
    int  my_src[16];
    float my_w[16];
#pragma unroll
    for (int k = 0; k < 4; ++k) {
        int e0 = c0 + (t + k * 256) * 4;
        if (e0 + 4 <= E) {
            int4 d4 = *(const int4*)(dst + e0);
            int4 s4 = *(const int4*)(src + e0);
            float4 w4 = *(const float4*)(w + e0);
            my_dst[k*4+0]=d4.x; my_dst[k*4+1]=d4.y; my_dst[k*4+2]=d4.z; my_dst[k*4+3]=d4.w;
            my_src[k*4+0]=s4.x; my_src[k*4+1]=s4.y; my_src[k*4+2]=s4.z; my_src[k*4+3]=s4.w;
            my_w[k*4+0]=w4.x;  my_w[k*4+1]=w4.y;  my_w[k*4+2]=w4.z;  my_w[k*4+3]=w4.w;
        } else {
#pragma unroll
            for (int j = 0; j < 4; ++j) {
                int e = e0 + j;
                bool ok = e < E;
                my_dst[k*4+j] = ok ? dst[e] : -1;
                my_src[k*4+j] = ok ? src[e] : 0;
                my_w[k*4+j]   = ok ? w[e] : 0.f;
            }
        }
    }
#pragma unroll
    for (int j = 0; j < 16; ++j)
        if (my_dst[j] >= 0) atomicAdd(&h[((unsigned)my_dst[j]) >> 8], 1);
    __syncthreads();

    int a0 = h[2 * t], a1 = h[2 * t + 1];
    int s = a0 + a1;
    part[t] = s;
    __syncthreads();
    for (int off = 1; off < 256; off <<= 1) {
        int v = part[t];
        int a = (t >= off) ? part[t - off] : 0;
        __syncthreads();
        part[t] = v + a;
        __syncthreads();
    }
    int excl = part[t] - s;
    lofs[2 * t] = excl;
    lofs[2 * t + 1] = excl + a0;
    if (a0) gb[2 * t] = atomicAdd(&gcur[2 * t], a0) - excl;
    if (a1) gb[2 * t + 1] = atomicAdd(&gcur[2 * t + 1], a1) - (excl + a0);
    __syncthreads();

#pragma unroll
    for (int j = 0; j < 16; ++j) {
        int d = my_dst[j];
        if (d < 0) continue;
        unsigned ud = (unsigned)d;
        int b = ud >> 8;
        int p = lofs[b] + atomicAdd(&lcnt[b], 1);
        int2 e;
        e.x = (int)(((ud & 255u) << 24) | (unsigned)my_src[j]);
        e.y = __float_as_int(my_w[j]);
        sedge[p] = e;
        sbuck[p] = (unsigned short)b;
    }
    __syncthreads();

    for (int i = t; i < mtile; i += 256) {
        int b = sbuck[i];
        bedge[gb[b] + i] = sedge[i];
    }
}

// ---- Pass D: per-bucket (node x quarter) counts + deg -> row_ptr, rp4, dinv.
__global__ void __launch_bounds__(256) sort_deg(const int* __restrict__ boff,
                                                const int2* __restrict__ bedge,
                                                int* __restrict__ row_ptr,
                                                int4* __restrict__ rp4,
                                                float* __restrict__ dinv,
                                                int N, int E, int qsize) {
    __shared__ int cnt[1024];
    __shared__ float deg[256];
    __shared__ int part[256];
    int b = blockIdx.x;
    int base = boff[b];
    int m = boff[b + 1] - base;
    int t = threadIdx.x;
    for (int i = t; i < 1024; i += 256) cnt[i] = 0;
    deg[t] = 0.f;
    __syncthreads();
    for (int i = t; i < m; i += 256) {
        int2 e = ldnt2(&bedge[base + i]);
        unsigned ux = (unsigned)e.x;
        unsigned l = ux >> 24;
        int sidx = (int)(ux & 0xFFFFFFu);
        int qr = (int)((unsigned)sidx / (unsigned)qsize);
        atomicAdd(&cnt[l * 4 + qr], 1);
        atomicAdd(&deg[l], __int_as_float(e.y));
    }
    __syncthreads();
    int c0 = cnt[t * 4], c1 = cnt[t * 4 + 1], c2 = cnt[t * 4 + 2], c3 = cnt[t * 4 + 3];
    int tot = c0 + c1 + c2 + c3;
    part[t] = tot;
    __syncthreads();
    for (int off = 1; off < 256; off <<= 1) {
        int v = part[t];
        int a = (t >= off) ? part[t - off] : 0;
        __syncthreads();
        part[t] = v + a;
        __syncthreads();
    }
    int excl = part[t] - tot;
    int node = b * 256 + t;
    if (node < N) {
        int beg = base + excl;
        row_ptr[node] = beg;
        rp4[node] = make_int4(beg, beg + c0, beg + c0 + c1, beg + c0 + c1 + c2);
        dinv[node] = rsqrtf(deg[t] + 1.0f);
    }
    if (b == 0 && t == 0) row_ptr[N] = E;
}

// ---- Pass E: bedge -> perm in (node, quarter) order, norm fused.
__global__ void __launch_bounds__(256) sort_scatter(const int* __restrict__ boff,
                                                    const int2* __restrict__ bedge,
                                                    const int4* __restrict__ rp4,
                                                    const float* __restrict__ dinv,
                                                    int2* __restrict__ perm,
                                                    int N, int qsize) {
    __shared__ int cur[1024];
    __shared__ float sdinv[256];
    int b = blockIdx.x;
    int base = boff[b];
    int m = boff[b + 1] - base;
    int t = threadIdx.x;
    int node = b * 256 + t;
    if (node < N) {
        int4 sg = rp4[node];
        cur[t * 4] = sg.x; cur[t * 4 + 1] = sg.y;
        cur[t * 4 + 2] = sg.z; cur[t * 4 + 3] = sg.w;
        sdinv[t] = dinv[node];
    } else {
        cur[t * 4] = cur[t * 4 + 1] = cur[t * 4 + 2] = cur[t * 4 + 3] = 0;
        sdinv[t] = 0.f;
    }
    __syncthreads();
    for (int i = t; i < m; i += 256) {
        int2 e = ldnt2(&bedge[base + i]);
        unsigned ux = (unsigned)e.x;
        unsigned l = ux >> 24;
        int sidx = (int)(ux & 0xFFFFFFu);
        int qr = (int)((unsigned)sidx / (unsigned)qsize);
        float nm = dinv[sidx] * __int_as_float(e.y) * sdinv[l];
        int pos = atomicAdd(&cur[l * 4 + qr], 1);
        perm[pos] = make_int2(sidx, __float_as_int(nm));
    }
}

// x[N,256] @ W[256,16] -> xw[N,16]. Non-temporal x reads (single use).
__global__ void __launch_bounds__(256) gemm_x16(const float* __restrict__ x,
                                                const float* __restrict__ W,
                                                float* __restrict__ xw, int N) {
    __shared__ float Ws[256 * 16];
    for (int i = threadIdx.x; i < 256 * 16; i += 256) Ws[i] = W[i];
    __syncthreads();
    int c = threadIdx.x & 15;
    int rl = threadIdx.x >> 4;
    int r = blockIdx.x * 16 + rl;
    if (r >= N) return;
    const float4* x4 = (const float4*)(x + (size_t)r * 256);
    float acc = 0.f;
#pragma unroll 8
    for (int k4 = 0; k4 < 64; ++k4) {
        float4 v = ldnt4(x4 + k4);
        const float* wr = &Ws[k4 * 64 + c];
        acc += v.x * wr[0] + v.y * wr[16] + v.z * wr[32] + v.w * wr[48];
    }
    xw[(size_t)r * 16 + c] = acc;
}

// in[N,K] @ W[K,F] + bias -> out[N,F], optional ELU on output.
template <int K, int F, bool OUT_ELU>
__global__ void __launch_bounds__(256) gemm_small(const float* __restrict__ in,
                                                  const float* __restrict__ W,
                                                  const float* __restrict__ bias,
                                                  float* __restrict__ out, int N) {
    constexpr int ROWS = 256 / F;
    __shared__ float Ws[K * F];
    __shared__ float Is[ROWS * K];
    for (int i = threadIdx.x; i < K * F; i += 256) Ws[i] = W[i];
    int r0 = blockIdx.x * ROWS;
    for (int i = threadIdx.x; i < ROWS * K; i += 256)
        Is[i] = in[(size_t)r0 * K + i];
    __syncthreads();
    int c = threadIdx.x % F;
    int rl = threadIdx.x / F;
    float acc = bias[c];
#pragma unroll
    for (int k = 0; k < K; ++k) acc += Is[rl * K + k] * Ws[k * F + c];
    if (OUT_ELU) acc = acc > 0.f ? acc : expm1f(acc);
    out[(size_t)(r0 + rl) * F + c] = acc;
}

// CSR gather-aggregate, phased over src-quarters (S quarters merged/phase).
template <int F, int S, bool BIAS_ELU>
__global__ void __launch_bounds__(256) agg4(const int4* __restrict__ rp4,
                                            const int* __restrict__ row_ptr,
                                            const int2* __restrict__ perm,
                                            const float* __restrict__ xw,
                                            const float* __restrict__ dinv,
                                            const float* __restrict__ bias,
                                            float* __restrict__ out, int N) {
    constexpr int G = F / 4;              // lanes per node
    constexpr int NPB = 256 / G;          // nodes per block
    int node = blockIdx.x * NPB + threadIdx.x / G;
    int q = threadIdx.x % G;
    if (node >= N) return;
    const float4* xw4 = (const float4*)xw;
    float di = dinv[node];
    float4 s = xw4[(size_t)node * G + q];
    float d2 = di * di;
    float4 a0 = {d2 * s.x, d2 * s.y, d2 * s.z, d2 * s.w};
    float4 a1 = {0.f, 0.f, 0.f, 0.f};
    float4 a2 = {0.f, 0.f, 0.f, 0.f};
    float4 a3 = {0.f, 0.f, 0.f, 0.f};
    int4 sg = rp4[node];
    int end = row_ptr[node + 1];
    int bnd[5] = {sg.x, sg.y, sg.z, sg.w, end};
#pragma unroll
    for (int p = 0; p < 4; p += S) {
        int j = bnd[p];
        int je = bnd[p + S];
        for (; j + 3 < je; j += 4) {
            int2 p0 = ldnt2(perm + j);
            int2 p1 = ldnt2(perm + j + 1);
            int2 p2 = ldnt2(perm + j + 2);
            int2 p3 = ldnt2(perm + j + 3);
            float4 v0 = xw4[(size_t)p0.x * G + q];
            float4 v1 = xw4[(size_t)p1.x * G + q];
            float4 v2 = xw4[(size_t)p2.x * G + q];
            float4 v3 = xw4[(size_t)p3.x * G + q];
            float n0 = __int_as_float(p0.y);
            float n1 = __int_as_float(p1.y);
            float n2 = __int_as_float(p2.y);
            float n3 = __int_as_float(p3.y);
            a0.x += n0 * v0.x; a0.y += n0 * v0.y; a0.z += n0 * v0.z; a0.w += n0 * v0.w;
            a1.x += n1 * v1.x; a1.y += n1 * v1.y; a1.z += n1 * v1.z; a1.w += n1 * v1.w;
            a2.x += n2 * v2.x; a2.y += n2 * v2.y; a2.z += n2 * v2.z; a2.w += n2 * v2.w;
            a3.x += n3 * v3.x; a3.y += n3 * v3.y; a3.z += n3 * v3.z; a3.w += n3 * v3.w;
        }
        for (; j < je; ++j) {
            int2 p0 = ldnt2(perm + j);
            float4 v0 = xw4[(size_t)p0.x * G + q];
            float n0 = __int_as_float(p0.y);
            a0.x += n0 * v0.x; a0.y += n0 * v0.y; a0.z += n0 * v0.z; a0.w += n0 * v0.w;
        }
    }
    float4 r;
    r.x = (a0.x + a1.x) + (a2.x + a3.x);
    r.y = (a0.y + a1.y) + (a2.y + a3.y);
    r.z = (a0.z + a1.z) + (a2.z + a3.z);
    r.w = (a0.w + a1.w) + (a2.w + a3.w);
    if (BIAS_ELU) {
        float4 b4 = ((const float4*)bias)[q];
        r.x += b4.x; r.y += b4.y; r.z += b4.z; r.w += b4.w;
        r.x = r.x > 0.f ? r.x : expm1f(r.x);
        r.y = r.y > 0.f ? r.y : expm1f(r.y);
        r.z = r.z > 0.f ? r.z : expm1f(r.z);
        r.w = r.w > 0.f ? r.w : expm1f(r.w);
    }
    stnt4((float4*)out + (size_t)node * G + q, r);
}

extern "C" void kernel_launch(void* const* d_in, const int* in_sizes, int n_in,
                              void* d_out, int out_size, void* d_ws, size_t ws_size,
                              hipStream_t stream) {
    const float* x  = (const float*)d_in[0];
    const int*   ei = (const int*)d_in[1];
    const float* w  = (const float*)d_in[2];
    const float* W0 = (const float*)d_in[3];
    const float* b0 = (const float*)d_in[4];
    const float* W1 = (const float*)d_in[5];
    const float* b1 = (const float*)d_in[6];
    const float* W2 = (const float*)d_in[7];
    const float* b2 = (const float*)d_in[8];
    const float* Wm = (const float*)d_in[9];
    const float* bm = (const float*)d_in[10];
    float* out = (float*)d_out;

    const int N = in_sizes[0] / 256;
    const int E = in_sizes[2];
    const int* src = ei;
    const int* dst = ei + E;
    const int nbuck = (N + 255) >> 8;   // 256 nodes per bucket
    const int qsize = (N + 3) / 4;      // src-quarter size

    char* ws = (char*)d_ws;
    size_t off = 0;
    auto alloc = [&](size_t bytes) {
        void* p = ws + off;
        off = (off + bytes + 255) & ~(size_t)255;
        return p;
    };
    float* dinv    = (float*)alloc((size_t)N * 4);
    int*   row_ptr = (int*)alloc(((size_t)N + 1) * 4);
    int4*  rp4     = (int4*)alloc((size_t)N * 16);
    int*   bcnt    = (int*)alloc(520 * 4);
    int*   boff    = (int*)alloc(520 * 4);
    int*   gcur    = (int*)alloc(520 * 4);
    int2*  bedge   = (int2*)alloc((size_t)E * 8);
    int2*  perm    = (int2*)alloc((size_t)E * 8);
    float* BUF_A   = (float*)alloc((size_t)N * 32 * 4);
    float* BUF_B   = (float*)alloc((size_t)N * 32 * 4);

    hipMemsetAsync(bcnt, 0, 520 * 4, stream);

    const int CH = 8192;
    const int sblk = (E + CH - 1) / CH;

    // ---- build CSR (layer-invariant)
    bucket_hist<<<sblk, 256, 0, stream>>>(dst, bcnt, E, nbuck, CH);
    bucket_scan<<<1, 512, 0, stream>>>(bcnt, boff, gcur, nbuck);
    bucket_scatter<<<(E + 4095) / 4096, 256, 0, stream>>>(src, dst, w, gcur, bedge, E);
    sort_deg<<<nbuck, 256, 0, stream>>>(boff, bedge, row_ptr, rp4, dinv, N, E, qsize);
    sort_scatter<<<nbuck, 256, 0, stream>>>(boff, bedge, rp4, dinv, perm, N, qsize);

    // ---- layer 0: XW = x@W0 ; h1 = elu(A.XW + b0)
    gemm_x16<<<(N + 15) / 16, 256, 0, stream>>>(x, W0, BUF_A, N);
    agg4<16, 2, true><<<(N + 63) / 64, 256, 0, stream>>>(rp4, row_ptr, perm, BUF_A, dinv, b0, BUF_B, N);

    // ---- layer 1: AG1 = A.h1 ; h2 = elu(AG1@W1 + b1)
    agg4<16, 2, false><<<(N + 63) / 64, 256, 0, stream>>>(rp4, row_ptr, perm, BUF_B, dinv, nullptr, BUF_A, N);
    gemm_small<16, 32, true><<<(N + 7) / 8, 256, 0, stream>>>(BUF_A, W1, b1, BUF_B, N);

    // ---- layer 2: AG2 = A.h2 ; h3 = elu(AG2@W2 + b2)
    agg4<32, 1, false><<<(N + 31) / 32, 256, 0, stream>>>(rp4, row_ptr, perm, BUF_B, dinv, nullptr, BUF_A, N);
    gemm_small<32, 32, true><<<(N + 7) / 8, 256, 0, stream>>>(BUF_A, W2, b2, BUF_B, N);

    // ---- head: out = h3@Wm + bm
    gemm_small<32, 16, false><<<(N + 15) / 16, 256, 0, stream>>>(BUF_B, Wm, bm, out, N);
}

// Round 7
// 756.952 us; speedup vs baseline: 1.0010x; 1.0010x over previous
//
#include <hip/hip_runtime.h>
#include <cstdint>

// ---------------------------------------------------------------------------
// GCN: 3x GCNConv(+ELU) + linear head.
// Edge list is sorted into (src-quarter, dst-node) order:
//   perm = 4 contiguous quarter segments; rpq[q][node] is a per-quarter CSR.
// Each aggregation pass runs as one LAUNCH per quarter phase -> all resident
// blocks gather from the same 1.6-3.2MB xw slice (fits 4MB per-XCD L2).
// Build (no per-edge global atomics, all writes coalesced):
//   A) bucket_hist   : per-bucket counts (bucket = dst>>7, 128 nodes)
//   B) bucket_scan   : prefix -> boff/gcur
//   C) bucket_scatter: LDS counting-sort of 4096-edge tiles -> bedge
//   D) sort_deg      : per-bucket deg -> dinv ; per-(bucket,quarter) totals
//   E) qscan         : scan totals in (q,bucket) order -> qbase
//   F) sort_scatter  : stage bucket in LDS in (q,node) order with norm fused,
//                      stream out 4 contiguous chunks; writes rpq
// ---------------------------------------------------------------------------

typedef float __attribute__((ext_vector_type(4))) f4v;

__device__ inline int2 ldnt2(const int2* p) {
    long long v = __builtin_nontemporal_load((const long long*)p);
    int2 r;
    r.x = (int)(unsigned)(v & 0xFFFFFFFFLL);
    r.y = (int)(unsigned)((unsigned long long)v >> 32);
    return r;
}
__device__ inline float4 ldnt4(const float4* p) {
    f4v v = __builtin_nontemporal_load((const f4v*)p);
    float4 r;
    r.x = v.x; r.y = v.y; r.z = v.z; r.w = v.w;
    return r;
}

__device__ inline int quarter_of(int sidx, float qscale) {
    int q = (int)((float)sidx * qscale);
    return q > 3 ? 3 : q;
}

// ---- Pass A: per-bucket edge counts. bucket = dst >> 7.
__global__ void __launch_bounds__(256) bucket_hist(const int* __restrict__ dst,
                                                   int* __restrict__ bcnt,
                                                   int E, int nbuck, int chunk) {
    __shared__ int h[1024];
    for (int i = threadIdx.x; i < 1024; i += 256) h[i] = 0;
    __syncthreads();
    int c0 = blockIdx.x * chunk;
    int c1 = min(E, c0 + chunk);
    for (int i = c0 + threadIdx.x; i < c1; i += 256)
        atomicAdd(&h[((unsigned)dst[i]) >> 7], 1);
    __syncthreads();
    for (int i = threadIdx.x; i < nbuck; i += 256)
        if (h[i]) atomicAdd(&bcnt[i], h[i]);
}

// ---- Pass B: scan 1024 bins (512 thr x 2) -> boff[0..1024], gcur.
__global__ void __launch_bounds__(512) bucket_scan(const int* __restrict__ bcnt,
                                                   int* __restrict__ boff,
                                                   int* __restrict__ gcur) {
    __shared__ int part[512];
    int t = threadIdx.x;
    int c0 = bcnt[2 * t], c1 = bcnt[2 * t + 1];
    int s = c0 + c1;
    part[t] = s;
    __syncthreads();
    for (int off = 1; off < 512; off <<= 1) {
        int v = part[t];
        int a = (t >= off) ? part[t - off] : 0;
        __syncthreads();
        part[t] = v + a;
        __syncthreads();
    }
    int excl = part[t] - s;
    boff[2 * t] = excl;     gcur[2 * t] = excl;
    boff[2 * t + 1] = excl + c0; gcur[2 * t + 1] = excl + c0;
    if (t == 511) boff[1024] = part[511];
}

// ---- Pass C: LDS-reorder scatter into bucket regions. TILE=4096.
// pack: (local_dst(7b) << 25) | src(25b)
__global__ void __launch_bounds__(256) bucket_scatter(const int* __restrict__ src,
                                                      const int* __restrict__ dst,
                                                      const float* __restrict__ w,
                                                      int* __restrict__ gcur,
                                                      int2* __restrict__ bedge,
                                                      int E) {
    constexpr int TILE = 4096;
    __shared__ int h[1024];
    __shared__ int lcnt[1024];
    __shared__ int lofs[1024];
    __shared__ int gb[1024];
    __shared__ int part[256];
    __shared__ int2 sedge[TILE];
    __shared__ unsigned short sbuck[TILE];

    int t = threadIdx.x;
    int c0 = blockIdx.x * TILE;
    int mtile = min(TILE, E - c0);

    for (int i = t; i < 1024; i += 256) { h[i] = 0; lcnt[i] = 0; }
    __syncthreads();

    int  my_dst[16];
    int  my_src[16];
    float my_w[16];
#pragma unroll
    for (int k = 0; k < 4; ++k) {
        int e0 = c0 + (t + k * 256) * 4;
        if (e0 + 4 <= E) {
            int4 d4 = *(const int4*)(dst + e0);
            int4 s4 = *(const int4*)(src + e0);
            float4 w4 = *(const float4*)(w + e0);
            my_dst[k*4+0]=d4.x; my_dst[k*4+1]=d4.y; my_dst[k*4+2]=d4.z; my_dst[k*4+3]=d4.w;
            my_src[k*4+0]=s4.x; my_src[k*4+1]=s4.y; my_src[k*4+2]=s4.z; my_src[k*4+3]=s4.w;
            my_w[k*4+0]=w4.x;  my_w[k*4+1]=w4.y;  my_w[k*4+2]=w4.z;  my_w[k*4+3]=w4.w;
        } else {
#pragma unroll
            for (int j = 0; j < 4; ++j) {
                int e = e0 + j;
                bool ok = e < E;
                my_dst[k*4+j] = ok ? dst[e] : -1;
                my_src[k*4+j] = ok ? src[e] : 0;
                my_w[k*4+j]   = ok ? w[e] : 0.f;
            }
        }
    }
#pragma unroll
    for (int j = 0; j < 16; ++j)
        if (my_dst[j] >= 0) atomicAdd(&h[((unsigned)my_dst[j]) >> 7], 1);
    __syncthreads();

    // 4 bins/thread scan + global reservation
    int h0 = h[4*t], h1 = h[4*t+1], h2 = h[4*t+2], h3 = h[4*t+3];
    int s = h0 + h1 + h2 + h3;
    part[t] = s;
    __syncthreads();
    for (int off = 1; off < 256; off <<= 1) {
        int v = part[t];
        int a = (t >= off) ? part[t - off] : 0;
        __syncthreads();
        part[t] = v + a;
        __syncthreads();
    }
    int excl = part[t] - s;
    lofs[4*t]   = excl;
    lofs[4*t+1] = excl + h0;
    lofs[4*t+2] = excl + h0 + h1;
    lofs[4*t+3] = excl + h0 + h1 + h2;
    if (h0) gb[4*t]   = atomicAdd(&gcur[4*t],   h0) - lofs[4*t];
    if (h1) gb[4*t+1] = atomicAdd(&gcur[4*t+1], h1) - lofs[4*t+1];
    if (h2) gb[4*t+2] = atomicAdd(&gcur[4*t+2], h2) - lofs[4*t+2];
    if (h3) gb[4*t+3] = atomicAdd(&gcur[4*t+3], h3) - lofs[4*t+3];
    __syncthreads();

#pragma unroll
    for (int j = 0; j < 16; ++j) {
        int d = my_dst[j];
        if (d < 0) continue;
        unsigned ud = (unsigned)d;
        int b = ud >> 7;
        int p = lofs[b] + atomicAdd(&lcnt[b], 1);
        int2 e;
        e.x = (int)(((ud & 127u) << 25) | (unsigned)my_src[j]);
        e.y = __float_as_int(my_w[j]);
        sedge[p] = e;
        sbuck[p] = (unsigned short)b;
    }
    __syncthreads();

    for (int i = t; i < mtile; i += 256) {
        int b = sbuck[i];
        bedge[gb[b] + i] = sedge[i];
    }
}

// ---- Pass D: per-bucket weighted degree -> dinv ; (bucket x quarter) totals.
__global__ void __launch_bounds__(256) sort_deg(const int* __restrict__ boff,
                                                const int2* __restrict__ bedge,
                                                float* __restrict__ dinv,
                                                int* __restrict__ bq,
                                                int N, float qscale) {
    __shared__ float deg[128];
    __shared__ int qcnt[4];
    int b = blockIdx.x;
    int base = boff[b];
    int m = boff[b + 1] - base;
    int t = threadIdx.x;
    if (t < 128) deg[t] = 0.f;
    if (t < 4) qcnt[t] = 0;
    __syncthreads();
    for (int i = t; i < m; i += 256) {
        int2 e = ldnt2(&bedge[base + i]);
        unsigned ux = (unsigned)e.x;
        unsigned l = ux >> 25;
        int sidx = (int)(ux & 0x1FFFFFFu);
        atomicAdd(&deg[l], __int_as_float(e.y));
        atomicAdd(&qcnt[quarter_of(sidx, qscale)], 1);
    }
    __syncthreads();
    int node = b * 128 + t;
    if (t < 128 && node < N) dinv[node] = rsqrtf(deg[t] + 1.0f);
    if (t < 4) bq[b * 4 + t] = qcnt[t];
}

// ---- Pass E: scan bq in (q, bucket) order -> qbase[q*nbuck+b].
__global__ void __launch_bounds__(512) qscan(const int* __restrict__ bq,
                                             int* __restrict__ qbase, int nbuck) {
    __shared__ int part[512];
    int t = threadIdx.x;
    int TOT = 4 * nbuck;
    int C = (TOT + 511) / 512;
    int beg = t * C;
    int end = min(TOT, beg + C);
    if (beg > TOT) beg = TOT;
    int s = 0;
    for (int i = beg; i < end; ++i) {
        int q = i / nbuck, b = i - q * nbuck;
        s += bq[b * 4 + q];
    }
    part[t] = s;
    __syncthreads();
    for (int off = 1; off < 512; off <<= 1) {
        int v = part[t];
        int a = (t >= off) ? part[t - off] : 0;
        __syncthreads();
        part[t] = v + a;
        __syncthreads();
    }
    int run = part[t] - s;
    for (int i = beg; i < end; ++i) {
        int q = i / nbuck, b = i - q * nbuck;
        qbase[i] = run;
        run += bq[b * 4 + q];
    }
}

// ---- Pass F: stage bucket in LDS in (q,node) order with fused norm, then
// stream out 4 contiguous chunks. Writes rpq (per-quarter CSR row starts).
__global__ void __launch_bounds__(256) sort_scatter(const int* __restrict__ boff,
                                                    const int2* __restrict__ bedge,
                                                    const int* __restrict__ qbase,
                                                    const float* __restrict__ dinv,
                                                    int2* __restrict__ perm,
                                                    int* __restrict__ rpq,
                                                    int N, int nbuck, float qscale,
                                                    int maxe) {
    extern __shared__ int2 sedge[];   // maxe entries
    __shared__ int cnt[512];
    __shared__ int ofs[513];
    __shared__ int cur[512];
    __shared__ int scanb[256];
    __shared__ float sdinv[128];
    __shared__ int qb[4];

    int b = blockIdx.x;
    int base = boff[b];
    int m = boff[b + 1] - base;
    int t = threadIdx.x;
    if (t < 4) qb[t] = qbase[t * nbuck + b];
    for (int i = t; i < 512; i += 256) cnt[i] = 0;
    if (t < 128) {
        int node = b * 128 + t;
        sdinv[t] = (node < N) ? dinv[node] : 0.f;
    }
    __syncthreads();

    // pass 1: per-(quarter,node) counts
    for (int i = t; i < m; i += 256) {
        int2 e = ldnt2(&bedge[base + i]);
        unsigned ux = (unsigned)e.x;
        unsigned l = ux >> 25;
        int sidx = (int)(ux & 0x1FFFFFFu);
        atomicAdd(&cnt[quarter_of(sidx, qscale) * 128 + l], 1);
    }
    __syncthreads();

    // scan 512 bins (2/thread), flattened (q,node) order
    int c0 = cnt[2 * t], c1 = cnt[2 * t + 1];
    int s = c0 + c1;
    scanb[t] = s;
    __syncthreads();
    for (int off = 1; off < 256; off <<= 1) {
        int v = scanb[t];
        int a = (t >= off) ? scanb[t - off] : 0;
        __syncthreads();
        scanb[t] = v + a;
        __syncthreads();
    }
    int excl = scanb[t] - s;
    ofs[2 * t] = excl;     cur[2 * t] = excl;
    ofs[2 * t + 1] = excl + c0; cur[2 * t + 1] = excl + c0;
    if (t == 255) ofs[512] = m;
    __syncthreads();

    // per-quarter CSR row starts
    if (t < 128) {
        int node = b * 128 + t;
        if (node < N) {
#pragma unroll
            for (int q = 0; q < 4; ++q)
                rpq[(size_t)q * (N + 1) + node] = qb[q] + (ofs[q * 128 + t] - ofs[q * 128]);
        }
    }
    if (b == nbuck - 1 && t < 4)
        rpq[(size_t)t * (N + 1) + N] = qb[t] + (ofs[(t + 1) * 128] - ofs[t * 128]);

    // pass 2: stage into LDS at final (q,node) position, norm fused
    for (int i = t; i < m; i += 256) {
        int2 e = ldnt2(&bedge[base + i]);
        unsigned ux = (unsigned)e.x;
        unsigned l = ux >> 25;
        int sidx = (int)(ux & 0x1FFFFFFu);
        int qr = quarter_of(sidx, qscale);
        float nm = dinv[sidx] * __int_as_float(e.y) * sdinv[l];
        int p = atomicAdd(&cur[qr * 128 + l], 1);
        int2 v = make_int2(sidx, __float_as_int(nm));
        if (p < maxe) sedge[p] = v;
        else perm[qb[qr] + (p - ofs[qr * 128])] = v;  // rare overflow path
    }
    __syncthreads();

    // stream out: 4 contiguous coalesced chunks
#pragma unroll
    for (int q = 0; q < 4; ++q) {
        int lb = ofs[q * 128];
        int le = ofs[(q + 1) * 128];
        int gbase = qb[q];
        int lim = min(le, maxe);
        for (int i = lb + t; i < lim; i += 256)
            perm[gbase + (i - lb)] = sedge[i];
    }
}

// x[N,256] @ W[256,16] -> xw[N,16].
__global__ void __launch_bounds__(256) gemm_x16(const float* __restrict__ x,
                                                const float* __restrict__ W,
                                                float* __restrict__ xw, int N) {
    __shared__ float Ws[256 * 16];
    for (int i = threadIdx.x; i < 256 * 16; i += 256) Ws[i] = W[i];
    __syncthreads();
    int c = threadIdx.x & 15;
    int rl = threadIdx.x >> 4;
    int r = blockIdx.x * 16 + rl;
    if (r >= N) return;
    const float4* x4 = (const float4*)(x + (size_t)r * 256);
    float acc = 0.f;
#pragma unroll 8
    for (int k4 = 0; k4 < 64; ++k4) {
        float4 v = ldnt4(x4 + k4);
        const float* wr = &Ws[k4 * 64 + c];
        acc += v.x * wr[0] + v.y * wr[16] + v.z * wr[32] + v.w * wr[48];
    }
    xw[(size_t)r * 16 + c] = acc;
}

// in[N,K] @ W[K,F] + bias -> out[N,F], optional ELU on output.
template <int K, int F, bool OUT_ELU>
__global__ void __launch_bounds__(256) gemm_small(const float* __restrict__ in,
                                                  const float* __restrict__ W,
                                                  const float* __restrict__ bias,
                                                  float* __restrict__ out, int N) {
    constexpr int ROWS = 256 / F;
    __shared__ float Ws[K * F];
    __shared__ float Is[ROWS * K];
    for (int i = threadIdx.x; i < K * F; i += 256) Ws[i] = W[i];
    int r0 = blockIdx.x * ROWS;
    for (int i = threadIdx.x; i < ROWS * K; i += 256)
        Is[i] = in[(size_t)r0 * K + i];
    __syncthreads();
    int c = threadIdx.x % F;
    int rl = threadIdx.x / F;
    float acc = bias[c];
#pragma unroll
    for (int k = 0; k < K; ++k) acc += Is[rl * K + k] * Ws[k * F + c];
    if (OUT_ELU) acc = acc > 0.f ? acc : expm1f(acc);
    out[(size_t)(r0 + rl) * F + c] = acc;
}

// ---- Quarter-phased gather-aggregate. One launch per phase (S quarters).
// flags: bit0 = init (self-loop + optional bias), bit1 = final (apply ELU).
template <int F, int S, bool ELU>
__global__ void __launch_bounds__(256) agg_q(const int* __restrict__ rpq,
                                             const int2* __restrict__ perm,
                                             const float* __restrict__ xw,
                                             const float* __restrict__ dinv,
                                             const float* __restrict__ bias,
                                             float* __restrict__ out,
                                             int N, int q0, int flags) {
    constexpr int G = F / 4;
    constexpr int NPB = 256 / G;
    int node = blockIdx.x * NPB + threadIdx.x / G;
    int q = threadIdx.x % G;
    if (node >= N) return;
    const float4* xw4 = (const float4*)xw;
    float4* out4 = (float4*)out;
    float4 a0, a1, a2, a3;
    if (flags & 1) {
        float di = dinv[node];
        float d2 = di * di;
        float4 s = xw4[(size_t)node * G + q];
        a0.x = d2 * s.x; a0.y = d2 * s.y; a0.z = d2 * s.z; a0.w = d2 * s.w;
        if (bias) {
            float4 b4 = ((const float4*)bias)[q];
            a0.x += b4.x; a0.y += b4.y; a0.z += b4.z; a0.w += b4.w;
        }
    } else {
        a0 = out4[(size_t)node * G + q];
    }
    a1 = make_float4(0.f, 0.f, 0.f, 0.f);
    a2 = a1; a3 = a1;
#pragma unroll
    for (int ss = 0; ss < S; ++ss) {
        const int* rp = rpq + (size_t)(q0 + ss) * (N + 1);
        int j = rp[node];
        int je = rp[node + 1];
        for (; j + 3 < je; j += 4) {
            int2 p0 = ldnt2(perm + j);
            int2 p1 = ldnt2(perm + j + 1);
            int2 p2 = ldnt2(perm + j + 2);
            int2 p3 = ldnt2(perm + j + 3);
            float4 v0 = xw4[(size_t)p0.x * G + q];
            float4 v1 = xw4[(size_t)p1.x * G + q];
            float4 v2 = xw4[(size_t)p2.x * G + q];
            float4 v3 = xw4[(size_t)p3.x * G + q];
            float n0 = __int_as_float(p0.y);
            float n1 = __int_as_float(p1.y);
            float n2 = __int_as_float(p2.y);
            float n3 = __int_as_float(p3.y);
            a0.x += n0 * v0.x; a0.y += n0 * v0.y; a0.z += n0 * v0.z; a0.w += n0 * v0.w;
            a1.x += n1 * v1.x; a1.y += n1 * v1.y; a1.z += n1 * v1.z; a1.w += n1 * v1.w;
            a2.x += n2 * v2.x; a2.y += n2 * v2.y; a2.z += n2 * v2.z; a2.w += n2 * v2.w;
            a3.x += n3 * v3.x; a3.y += n3 * v3.y; a3.z += n3 * v3.z; a3.w += n3 * v3.w;
        }
        for (; j < je; ++j) {
            int2 p0 = ldnt2(perm + j);
            float4 v0 = xw4[(size_t)p0.x * G + q];
            float n0 = __int_as_float(p0.y);
            a0.x += n0 * v0.x; a0.y += n0 * v0.y; a0.z += n0 * v0.z; a0.w += n0 * v0.w;
        }
    }
    float4 r;
    r.x = (a0.x + a1.x) + (a2.x + a3.x);
    r.y = (a0.y + a1.y) + (a2.y + a3.y);
    r.z = (a0.z + a1.z) + (a2.z + a3.z);
    r.w = (a0.w + a1.w) + (a2.w + a3.w);
    if (ELU && (flags & 2)) {
        r.x = r.x > 0.f ? r.x : expm1f(r.x);
        r.y = r.y > 0.f ? r.y : expm1f(r.y);
        r.z = r.z > 0.f ? r.z : expm1f(r.z);
        r.w = r.w > 0.f ? r.w : expm1f(r.w);
    }
    out4[(size_t)node * G + q] = r;
}

extern "C" void kernel_launch(void* const* d_in, const int* in_sizes, int n_in,
                              void* d_out, int out_size, void* d_ws, size_t ws_size,
                              hipStream_t stream) {
    const float* x  = (const float*)d_in[0];
    const int*   ei = (const int*)d_in[1];
    const float* w  = (const float*)d_in[2];
    const float* W0 = (const float*)d_in[3];
    const float* b0 = (const float*)d_in[4];
    const float* b1 = (const float*)d_in[6];
    const float* W1 = (const float*)d_in[5];
    const float* W2 = (const float*)d_in[7];
    const float* b2 = (const float*)d_in[8];
    const float* Wm = (const float*)d_in[9];
    const float* bm = (const float*)d_in[10];
    float* out = (float*)d_out;

    const int N = in_sizes[0] / 256;
    const int E = in_sizes[2];
    const int* src = ei;
    const int* dst = ei + E;
    const int nbuck = (N + 127) >> 7;          // 128 nodes/bucket (<=1024 buckets)
    const float qscale = 4.0f / (float)(((N + 3) / 4) * 4);
    const int MAXE = 9216;                      // LDS staging capacity (edges)

    char* ws = (char*)d_ws;
    size_t off = 0;
    auto alloc = [&](size_t bytes) {
        void* p = ws + off;
        off = (off + bytes + 255) & ~(size_t)255;
        return p;
    };
    float* dinv  = (float*)alloc((size_t)N * 4);
    int*   rpq   = (int*)alloc((size_t)4 * (N + 1) * 4);
    int*   bcnt  = (int*)alloc(1040 * 4);
    int*   boff  = (int*)alloc(1040 * 4);
    int*   gcur  = (int*)alloc(1040 * 4);
    int*   bq    = (int*)alloc(4160 * 4);
    int*   qbase = (int*)alloc(4160 * 4);
    int2*  bedge = (int2*)alloc((size_t)E * 8);
    int2*  perm  = (int2*)alloc((size_t)E * 8);
    float* BUF_A = (float*)alloc((size_t)N * 32 * 4);
    float* BUF_B = (float*)alloc((size_t)N * 32 * 4);

    hipMemsetAsync(bcnt, 0, 1024 * 4, stream);

    const int CH = 8192;
    const int sblk = (E + CH - 1) / CH;

    // ---- build quarter-phased CSR (layer-invariant)
    bucket_hist<<<sblk, 256, 0, stream>>>(dst, bcnt, E, nbuck, CH);
    bucket_scan<<<1, 512, 0, stream>>>(bcnt, boff, gcur);
    bucket_scatter<<<(E + 4095) / 4096, 256, 0, stream>>>(src, dst, w, gcur, bedge, E);
    sort_deg<<<nbuck, 256, 0, stream>>>(boff, bedge, dinv, bq, N, qscale);
    qscan<<<1, 512, 0, stream>>>(bq, qbase, nbuck);
    sort_scatter<<<nbuck, 256, MAXE * sizeof(int2), stream>>>(
        boff, bedge, qbase, dinv, perm, rpq, N, nbuck, qscale, MAXE);

    // ---- layer 0: XW = x@W0 ; h1 = elu(A.XW + b0)   [2 phases of 2 quarters]
    gemm_x16<<<(N + 15) / 16, 256, 0, stream>>>(x, W0, BUF_A, N);
    agg_q<16, 2, true><<<(N + 63) / 64, 256, 0, stream>>>(rpq, perm, BUF_A, dinv, b0, BUF_B, N, 0, 1);
    agg_q<16, 2, true><<<(N + 63) / 64, 256, 0, stream>>>(rpq, perm, BUF_A, dinv, b0, BUF_B, N, 2, 2);

    // ---- layer 1: AG1 = A.h1 ; h2 = elu(AG1@W1 + b1)
    agg_q<16, 2, false><<<(N + 63) / 64, 256, 0, stream>>>(rpq, perm, BUF_B, dinv, nullptr, BUF_A, N, 0, 1);
    agg_q<16, 2, false><<<(N + 63) / 64, 256, 0, stream>>>(rpq, perm, BUF_B, dinv, nullptr, BUF_A, N, 2, 2);
    gemm_small<16, 32, true><<<(N + 7) / 8, 256, 0, stream>>>(BUF_A, W1, b1, BUF_B, N);

    // ---- layer 2: AG2 = A.h2 ; h3 = elu(AG2@W2 + b2)   [4 phases of 1 quarter]
    agg_q<32, 1, false><<<(N + 31) / 32, 256, 0, stream>>>(rpq, perm, BUF_B, dinv, nullptr, BUF_A, N, 0, 1);
    agg_q<32, 1, false><<<(N + 31) / 32, 256, 0, stream>>>(rpq, perm, BUF_B, dinv, nullptr, BUF_A, N, 1, 0);
    agg_q<32, 1, false><<<(N + 31) / 32, 256, 0, stream>>>(rpq, perm, BUF_B, dinv, nullptr, BUF_A, N, 2, 0);
    agg_q<32, 1, false><<<(N + 31) / 32, 256, 0, stream>>>(rpq, perm, BUF_B, dinv, nullptr, BUF_A, N, 3, 2);
    gemm_small<32, 32, true><<<(N + 7) / 8, 256, 0, stream>>>(BUF_A, W2, b2, BUF_B, N);

    // ---- head: out = h3@Wm + bm
    gemm_small<32, 16, false><<<(N + 15) / 16, 256, 0, stream>>>(BUF_B, Wm, bm, out, N);
}